// Round 7
// baseline (73.566 us; speedup 1.0000x reference)
//
#include <hip/hip_runtime.h>

// ColorDenseCRFLoss via 32x32x16 MFMA + triangle symmetry.
// out = -1e-7/4 * sum_{n,p,q} exp(-0.5*||f_p-f_q||^2) * (seg_p . seg_q)
// R7: eliminate the crf_reduce kernel node (~4-9us of launch/gap) with a
// FENCE-FREE fused tail. R4's disaster was (a) per-block __threadfence and
// (b) 33 counters packed into 2 cache lines (2048 RMWs bouncing one line).
// Here: partial travels THROUGH atomicAdd (coherent, no release needed)
// into 64 acc slots spread 128B apart; 32 group counters spread 128B apart;
// 1 root. Per-block ordering acc-add -> counter-add enforced by consuming
// the atomic return value (forces vmcnt wait). Winner block re-reads slots
// via atomicAdd(&slot, 0.0f). No fence, no spin, no line sharing.

#define N_BATCH 4
#define IH 128
#define IW 128
#define P 4096   // 64x64 downsampled pixels per batch
#define KC 21

using short8   = __attribute__((ext_vector_type(8))) short;
using floatx16 = __attribute__((ext_vector_type(16))) float;

static constexpr float INV_SIGMA = 1.0f / 15.0f;
static constexpr float LOG2E     = 1.4426950408889634f;
static constexpr float OUT_SCALE = -1e-7f / 4.0f;

// ws layout (bytes):
//   [0,64) zero page; argA/argB: rows x 32B; seg: rows x 48B;
//   acc: 64 slots spread 128B; cnt: 33 slots spread 128B
#define ZP_OFF   0
#define ARGA_OFF 64
#define ARGB_OFF (ARGA_OFF + N_BATCH * P * 32)
#define SEG_OFF  (ARGB_OFF + N_BATCH * P * 32)
#define ACC_OFF  (SEG_OFF + N_BATCH * P * 48)
#define CNT_OFF  (ACC_OFF + 64 * 128)

#define NFEAT (N_BATCH * P)              // 16384
#define NSEG2 (N_BATCH * KC * P / 2)     // 172032 (2 pixels/thread)

#define CHUNKS 32
#define NBLOCKS (CHUNKS * 16 * N_BATCH)  // 2048 crf_pair blocks (32 groups x 64)

__device__ __forceinline__ ushort f2bf(float x) {  // RNE float->bf16 bits
    unsigned u = __builtin_bit_cast(unsigned, x);
    unsigned r = (u + 0x7FFFu + ((u >> 16) & 1u)) >> 16;
    return (ushort)r;
}
__device__ __forceinline__ float bf2f(ushort h) {
    return __builtin_bit_cast(float, (unsigned)h << 16);
}

__global__ void crf_prep(const float* __restrict__ img,
                         const float* __restrict__ seg,
                         char* __restrict__ wsb)
{
    int t = blockIdx.x * blockDim.x + threadIdx.x;
    if (t < NFEAT) {
        if (t < 16) ((float*)(wsb + ZP_OFF))[t] = 0.0f;            // zero page
        else if (t < 80) ((float*)(wsb + ACC_OFF))[(t - 16) * 32] = 0.0f;
        else if (t < 113) ((int*)(wsb + CNT_OFF))[(t - 80) * 32] = 0;

        int n = t >> 12;
        int p = t & (P - 1);
        int y = p >> 6, x = p & 63;

        const float* ib = img + (size_t)n * 3 * IH * IW + (size_t)(2 * y) * IW + 2 * x;
        float f0 = ib[0] * INV_SIGMA;
        float f1 = ib[IH * IW] * INV_SIGMA;
        float f2 = ib[2 * IH * IW] * INV_SIGMA;
        float h = 0.5f * (f0 * f0 + f1 * f1 + f2 * f2);

        float fa0 = f0 * LOG2E, fa1 = f1 * LOG2E, fa2 = f2 * LOG2E;
        ushort ah0 = f2bf(fa0), ah1 = f2bf(fa1), ah2 = f2bf(fa2);
        ushort al0 = f2bf(fa0 - bf2f(ah0));
        ushort al1 = f2bf(fa1 - bf2f(ah1));
        ushort al2 = f2bf(fa2 - bf2f(ah2));
        float nhL = -h * LOG2E;
        ushort nhh = f2bf(nhL), nhl = f2bf(nhL - bf2f(nhh));
        ushort bh0 = f2bf(f0), bh1 = f2bf(f1), bh2 = f2bf(f2);
        ushort bl0 = f2bf(f0 - bf2f(bh0));
        ushort bl1 = f2bf(f1 - bf2f(bh1));
        ushort bl2 = f2bf(f2 - bf2f(bh2));
        float hL = h * LOG2E;
        ushort hbh = f2bf(hL), hbl = f2bf(hL - bf2f(hbh));

        const ushort ONE = 0x3F80, NEG1 = 0xBF80;
        // dot(argA_p, argB_q) = log2e * (f_p.f_q - h_p - h_q), exactly K=16
        ushort rA[16] = {ah0, ah1, ah2, ah0, ah1, ah2, al0, al1, al2, al0, al1, al2,
                         nhh, nhl, NEG1, NEG1};
        ushort rB[16] = {bh0, bh1, bh2, bl0, bl1, bl2, bh0, bh1, bh2, bl0, bl1, bl2,
                         ONE, ONE, hbh, hbl};

        short8 vA0, vA1, vB0, vB1;
#pragma unroll
        for (int j = 0; j < 8; ++j) {
            vA0[j] = (short)rA[j];     vA1[j] = (short)rA[8 + j];
            vB0[j] = (short)rB[j];     vB1[j] = (short)rB[8 + j];
        }
        short8* dA = (short8*)(wsb + ARGA_OFF + (size_t)t * 32);
        dA[0] = vA0; dA[1] = vA1;
        short8* dB = (short8*)(wsb + ARGB_OFF + (size_t)t * 32);
        dB[0] = vB0; dB[1] = vB1;

        char* sp = wsb + SEG_OFF + (size_t)t * 48;   // zero seg pad k=21..23
        *(ushort*)(sp + 42) = 0;
        *(uint*)(sp + 44) = 0;
    } else if (t < NFEAT + NSEG2) {
        int u = t - NFEAT;
        int pp = (u & 2047) * 2;     // pixel pair base (even)
        int nk = u >> 11;            // n*21 + k
        int n = nk / 21;
        int k = nk - n * 21;
        int y = pp >> 6, x0 = pp & 63;

        const float* r0 = seg + (size_t)nk * IH * IW + (size_t)(2 * y) * IW + 2 * x0;
        float4 a = *(const float4*)r0;
        float4 b = *(const float4*)(r0 + IW);
        float v0 = 0.25f * ((a.x + a.y) + (b.x + b.y));
        float v1 = 0.25f * ((a.z + a.w) + (b.z + b.w));
        char* d = wsb + SEG_OFF + (size_t)(n * P + pp) * 48 + k * 2;
        *(ushort*)d = f2bf(v0);
        *(ushort*)(d + 48) = f2bf(v1);
    }
}

__global__ __launch_bounds__(256, 4) void crf_pair(char* __restrict__ wsb,
                                                   float* __restrict__ out)
{
    const int n    = blockIdx.z;
    const int sp   = blockIdx.y;          // strip pair [0,16): strips sp, 31-sp
    const int c    = blockIdx.x;          // j-chunk [0,CHUNKS)
    const int wave = threadIdx.x >> 6;    // i-tile within strip [0,4)
    const int lane = threadIdx.x & 63;
    const int l32  = lane & 31;
    const int l5   = lane >> 5;           // k-half select

    const char* argA = wsb + ARGA_OFF + (size_t)n * P * 32;
    const char* argB = wsb + ARGB_OFF + (size_t)n * P * 32;
    const char* segT = wsb + SEG_OFF  + (size_t)n * P * 48;
    const char* zp   = wsb + ZP_OFF;

    // B-side per-lane bases; j-tile strides 1024B (arg) / 1536B (seg)
    const char* bBa = argB + l32 * 32 + l5 * 16;
    const char* bBs = segT + l32 * 48 + l5 * 16;
    const int maskH = l5 ? 0 : ~0;        // hi seg half: k>=24 is zero pad
    const char* bBh = l5 ? zp : (segT + l32 * 48 + 32);

    const floatx16 zc = {0.f,0.f,0.f,0.f,0.f,0.f,0.f,0.f,
                         0.f,0.f,0.f,0.f,0.f,0.f,0.f,0.f};

    short8 afA, afL, afH;                 // A fragments for current phase

    float m0=0.f, m1=0.f, m2=0.f, m3=0.f; // weight-2 partials
    float d0=0.f, d1=0.f, d2=0.f, d3=0.f; // weight-1 (diag tile) partials

    auto jobM = [&](short8 ba, short8 bl, short8 bh) {
        floatx16 ar = __builtin_amdgcn_mfma_f32_32x32x16_bf16(afA, ba, zc, 0, 0, 0);
        floatx16 g  = __builtin_amdgcn_mfma_f32_32x32x16_bf16(afL, bl, zc, 0, 0, 0);
        g = __builtin_amdgcn_mfma_f32_32x32x16_bf16(afH, bh, g, 0, 0, 0);
#pragma unroll
        for (int r = 0; r < 16; ++r) {
            float t = __builtin_amdgcn_exp2f(ar[r]) * g[r];
            if ((r & 3) == 0) m0 += t;
            else if ((r & 3) == 1) m1 += t;
            else if ((r & 3) == 2) m2 += t;
            else m3 += t;
        }
    };
    auto jobD = [&](short8 ba, short8 bl, short8 bh) {
        floatx16 ar = __builtin_amdgcn_mfma_f32_32x32x16_bf16(afA, ba, zc, 0, 0, 0);
        floatx16 g  = __builtin_amdgcn_mfma_f32_32x32x16_bf16(afL, bl, zc, 0, 0, 0);
        g = __builtin_amdgcn_mfma_f32_32x32x16_bf16(afH, bh, g, 0, 0, 0);
#pragma unroll
        for (int r = 0; r < 16; ++r) {
            float t = __builtin_amdgcn_exp2f(ar[r]) * g[r];
            if ((r & 3) == 0) d0 += t;
            else if ((r & 3) == 1) d1 += t;
            else if ((r & 3) == 2) d2 += t;
            else d3 += t;
        }
    };

    auto load_A = [&](int ti) {
        int rr = ti * 32 + l32;
        afA = *(const short8*)(argA + rr * 32 + l5 * 16);
        afL = *(const short8*)(segT + rr * 48 + l5 * 16);
        afH = l5 ? *(const short8*)zp : *(const short8*)(segT + rr * 48 + 32);
    };

    // Main phase: j-tiles jbase+c, +CHUNKS, ... while index < jbase+cnt.
    // 2-slot ping-pong; reload a slot right after its MFMAs consumed it.
    auto run_main = [&](int jbase, int cnt) {
        if (cnt <= c) return;
        int nj = (cnt - c + CHUNKS - 1) / CHUNKS;
        int j0 = jbase + c;
        int oA0 = j0 * 1024, oS0 = j0 * 1536;
        int oA1 = oA0 + CHUNKS * 1024, oS1 = oS0 + CHUNKS * 1536;
        short8 a0 = *(const short8*)(bBa + oA0);
        short8 l0 = *(const short8*)(bBs + oS0);
        short8 h0 = *(const short8*)(bBh + (oS0 & maskH));
        short8 a1 = a0, l1 = l0, h1 = h0;
        if (nj > 1) {
            a1 = *(const short8*)(bBa + oA1);
            l1 = *(const short8*)(bBs + oS1);
            h1 = *(const short8*)(bBh + (oS1 & maskH));
        }
        for (int t = 0; t < nj; t += 2) {
            jobM(a0, l0, h0);
            if (t + 2 < nj) {
                oA0 += 2 * CHUNKS * 1024; oS0 += 2 * CHUNKS * 1536;
                a0 = *(const short8*)(bBa + oA0);
                l0 = *(const short8*)(bBs + oS0);
                h0 = *(const short8*)(bBh + (oS0 & maskH));
            }
            if (t + 1 < nj) {
                jobM(a1, l1, h1);
                if (t + 3 < nj) {
                    oA1 += 2 * CHUNKS * 1024; oS1 += 2 * CHUNKS * 1536;
                    a1 = *(const short8*)(bBa + oA1);
                    l1 = *(const short8*)(bBs + oS1);
                    h1 = *(const short8*)(bBh + (oS1 & maskH));
                }
            }
        }
    };

    // Strip-diagonal 4x4 tile block: wave ii handles j-tiles [4s+ii, 4s+4).
    auto run_edge = [&](int s) {
        for (int jj = wave; jj < 4; ++jj) {
            int j = 4 * s + jj;
            int oA = j * 1024, oS = j * 1536;
            short8 ba = *(const short8*)(bBa + oA);
            short8 bl = *(const short8*)(bBs + oS);
            short8 bh = *(const short8*)(bBh + (oS & maskH));
            if (jj == wave) jobD(ba, bl, bh);   // diag tile, weight 1 (symmetric)
            else           jobM(ba, bl, bh);    // off-diag, weight 2
        }
    };

    const int s0 = sp, s1 = 31 - sp;

    load_A(4 * s0 + wave);
    run_main(4 * s0 + 4, 124 - 4 * sp);
    if (c == CHUNKS - 1) run_edge(s0);

    load_A(4 * s1 + wave);
    run_main(4 * s1 + 4, 4 * sp);
    if (c == CHUNKS - 2) run_edge(s1);

    float part = 2.0f * ((m0 + m1) + (m2 + m3)) + ((d0 + d1) + (d2 + d3));
#pragma unroll
    for (int off = 32; off > 0; off >>= 1)
        part += __shfl_down(part, off, 64);
    __shared__ float wsum[4];
    __shared__ int winner;
    if (lane == 0) wsum[wave] = part;
    __syncthreads();

    float* acc = (float*)(wsb + ACC_OFF);    // 64 slots, 128B apart
    int*   cnt = (int*)(wsb + CNT_OFF);      // 33 slots, 128B apart
    if (threadIdx.x == 0) {
        float bsum = (wsum[0] + wsum[1]) + (wsum[2] + wsum[3]);
        int blin = (n * 16 + sp) * CHUNKS + c;        // [0, NBLOCKS)
        // partial travels through the atomic (coherent); consume return value
        // to force completion before the counter atomic (per-thread ordering)
        float old = atomicAdd(&acc[(blin & 63) * 32], bsum);
        asm volatile("" :: "v"(old));
        int w = 0;
        if (atomicAdd(&cnt[(blin >> 6) * 32], 1) == 63)   // last of 64-block group
            if (atomicAdd(&cnt[32 * 32], 1) == 31)        // last of 32 groups
                w = 1;
        winner = w;
    }
    __syncthreads();
    if (winner && threadIdx.x < 64) {        // wave 0 of last-arriving block
        float v = atomicAdd(&acc[threadIdx.x * 32], 0.0f);   // coherent read
#pragma unroll
        for (int off = 32; off > 0; off >>= 1)
            v += __shfl_down(v, off, 64);
        if (threadIdx.x == 0) out[0] = v * OUT_SCALE;
    }
}

extern "C" void kernel_launch(void* const* d_in, const int* in_sizes, int n_in,
                              void* d_out, int out_size, void* d_ws, size_t ws_size,
                              hipStream_t stream)
{
    const float* images = (const float*)d_in[0];   // [4,3,128,128]
    const float* segm   = (const float*)d_in[1];   // [4,21,128,128]
    float* out = (float*)d_out;                    // [1]
    char* wsb = (char*)d_ws;                       // ~1.85 MB used

    int prep_threads = NFEAT + NSEG2;
    crf_prep<<<dim3((prep_threads + 255) / 256), dim3(256), 0, stream>>>(
        images, segm, wsb);
    crf_pair<<<dim3(CHUNKS, 16, N_BATCH), dim3(256), 0, stream>>>(wsb, out);
}

// Round 8
// 73.518 us; speedup vs baseline: 1.0007x; 1.0007x over previous
//
#include <hip/hip_runtime.h>

// ColorDenseCRFLoss via 32x32x16 MFMA + triangle symmetry.
// out = -1e-7/4 * sum_{n,p,q} exp(-0.5*||f_p-f_q||^2) * (seg_p . seg_q)
// R8: R6 structure (store + 1-block reduce; fused tails lose: R4 +41, R7 +2).
// Change: run_main pipeline depth 2 -> 4 static slots. Evidence: pair body
// ~15us vs ~2us issue floor (R3/R4 differential), TLP doubling null (R6),
// => latency-bound with insufficient ILP depth. B-tiles arrive from L3/HBM
// (~400-900cyc) after kernel-boundary flush; depth-4 + 7 waves/SIMD covers
// ~4x more outstanding latency. VGPR ~72-90 (cap 128, no spill).

#define N_BATCH 4
#define IH 128
#define IW 128
#define P 4096   // 64x64 downsampled pixels per batch
#define KC 21

using short8   = __attribute__((ext_vector_type(8))) short;
using floatx16 = __attribute__((ext_vector_type(16))) float;

static constexpr float INV_SIGMA = 1.0f / 15.0f;
static constexpr float LOG2E     = 1.4426950408889634f;
static constexpr float OUT_SCALE = -1e-7f / 4.0f;

// ws layout (bytes):
//   [0,64)  zero page; argA/argB: rows x 32B; seg: rows x 48B; partials
#define ZP_OFF   0
#define ARGA_OFF 64
#define ARGB_OFF (ARGA_OFF + N_BATCH * P * 32)
#define SEG_OFF  (ARGB_OFF + N_BATCH * P * 32)
#define PART_OFF (SEG_OFF + N_BATCH * P * 48)   // 2048 floats

#define NFEAT (N_BATCH * P)              // 16384
#define NSEG2 (N_BATCH * KC * P / 2)     // 172032 (2 pixels/thread)

#define CHUNKS 32
#define NBLOCKS (CHUNKS * 16 * N_BATCH)  // 2048 crf_pair blocks

__device__ __forceinline__ ushort f2bf(float x) {  // RNE float->bf16 bits
    unsigned u = __builtin_bit_cast(unsigned, x);
    unsigned r = (u + 0x7FFFu + ((u >> 16) & 1u)) >> 16;
    return (ushort)r;
}
__device__ __forceinline__ float bf2f(ushort h) {
    return __builtin_bit_cast(float, (unsigned)h << 16);
}

__global__ void crf_prep(const float* __restrict__ img,
                         const float* __restrict__ seg,
                         char* __restrict__ wsb)
{
    int t = blockIdx.x * blockDim.x + threadIdx.x;
    if (t < NFEAT) {
        if (t < 16) ((float*)(wsb + ZP_OFF))[t] = 0.0f;  // zero page

        int n = t >> 12;
        int p = t & (P - 1);
        int y = p >> 6, x = p & 63;

        const float* ib = img + (size_t)n * 3 * IH * IW + (size_t)(2 * y) * IW + 2 * x;
        float f0 = ib[0] * INV_SIGMA;
        float f1 = ib[IH * IW] * INV_SIGMA;
        float f2 = ib[2 * IH * IW] * INV_SIGMA;
        float h = 0.5f * (f0 * f0 + f1 * f1 + f2 * f2);

        float fa0 = f0 * LOG2E, fa1 = f1 * LOG2E, fa2 = f2 * LOG2E;
        ushort ah0 = f2bf(fa0), ah1 = f2bf(fa1), ah2 = f2bf(fa2);
        ushort al0 = f2bf(fa0 - bf2f(ah0));
        ushort al1 = f2bf(fa1 - bf2f(ah1));
        ushort al2 = f2bf(fa2 - bf2f(ah2));
        float nhL = -h * LOG2E;
        ushort nhh = f2bf(nhL), nhl = f2bf(nhL - bf2f(nhh));
        ushort bh0 = f2bf(f0), bh1 = f2bf(f1), bh2 = f2bf(f2);
        ushort bl0 = f2bf(f0 - bf2f(bh0));
        ushort bl1 = f2bf(f1 - bf2f(bh1));
        ushort bl2 = f2bf(f2 - bf2f(bh2));
        float hL = h * LOG2E;
        ushort hbh = f2bf(hL), hbl = f2bf(hL - bf2f(hbh));

        const ushort ONE = 0x3F80, NEG1 = 0xBF80;
        // dot(argA_p, argB_q) = log2e * (f_p.f_q - h_p - h_q), exactly K=16
        ushort rA[16] = {ah0, ah1, ah2, ah0, ah1, ah2, al0, al1, al2, al0, al1, al2,
                         nhh, nhl, NEG1, NEG1};
        ushort rB[16] = {bh0, bh1, bh2, bl0, bl1, bl2, bh0, bh1, bh2, bl0, bl1, bl2,
                         ONE, ONE, hbh, hbl};

        short8 vA0, vA1, vB0, vB1;
#pragma unroll
        for (int j = 0; j < 8; ++j) {
            vA0[j] = (short)rA[j];     vA1[j] = (short)rA[8 + j];
            vB0[j] = (short)rB[j];     vB1[j] = (short)rB[8 + j];
        }
        short8* dA = (short8*)(wsb + ARGA_OFF + (size_t)t * 32);
        dA[0] = vA0; dA[1] = vA1;
        short8* dB = (short8*)(wsb + ARGB_OFF + (size_t)t * 32);
        dB[0] = vB0; dB[1] = vB1;

        char* sp = wsb + SEG_OFF + (size_t)t * 48;   // zero seg pad k=21..23
        *(ushort*)(sp + 42) = 0;
        *(uint*)(sp + 44) = 0;
    } else if (t < NFEAT + NSEG2) {
        int u = t - NFEAT;
        int pp = (u & 2047) * 2;     // pixel pair base (even)
        int nk = u >> 11;            // n*21 + k
        int n = nk / 21;
        int k = nk - n * 21;
        int y = pp >> 6, x0 = pp & 63;

        const float* r0 = seg + (size_t)nk * IH * IW + (size_t)(2 * y) * IW + 2 * x0;
        float4 a = *(const float4*)r0;
        float4 b = *(const float4*)(r0 + IW);
        float v0 = 0.25f * ((a.x + a.y) + (b.x + b.y));
        float v1 = 0.25f * ((a.z + a.w) + (b.z + b.w));
        char* d = wsb + SEG_OFF + (size_t)(n * P + pp) * 48 + k * 2;
        *(ushort*)d = f2bf(v0);
        *(ushort*)(d + 48) = f2bf(v1);
    }
}

__global__ __launch_bounds__(256, 4) void crf_pair(char* __restrict__ wsb)
{
    const int n    = blockIdx.z;
    const int sp   = blockIdx.y;          // strip pair [0,16): strips sp, 31-sp
    const int c    = blockIdx.x;          // j-chunk [0,CHUNKS)
    const int wave = threadIdx.x >> 6;    // i-tile within strip [0,4)
    const int lane = threadIdx.x & 63;
    const int l32  = lane & 31;
    const int l5   = lane >> 5;           // k-half select

    const char* argA = wsb + ARGA_OFF + (size_t)n * P * 32;
    const char* argB = wsb + ARGB_OFF + (size_t)n * P * 32;
    const char* segT = wsb + SEG_OFF  + (size_t)n * P * 48;
    const char* zp   = wsb + ZP_OFF;

    // B-side per-lane bases; j-tile strides 1024B (arg) / 1536B (seg)
    const char* bBa = argB + l32 * 32 + l5 * 16;
    const char* bBs = segT + l32 * 48 + l5 * 16;
    const int maskH = l5 ? 0 : ~0;        // hi seg half: k>=24 is zero pad
    const char* bBh = l5 ? zp : (segT + l32 * 48 + 32);

    const floatx16 zc = {0.f,0.f,0.f,0.f,0.f,0.f,0.f,0.f,
                         0.f,0.f,0.f,0.f,0.f,0.f,0.f,0.f};

    short8 afA, afL, afH;                 // A fragments for current phase

    float m0=0.f, m1=0.f, m2=0.f, m3=0.f; // weight-2 partials
    float d0=0.f, d1=0.f, d2=0.f, d3=0.f; // weight-1 (diag tile) partials

    auto jobM = [&](short8 ba, short8 bl, short8 bh) {
        floatx16 ar = __builtin_amdgcn_mfma_f32_32x32x16_bf16(afA, ba, zc, 0, 0, 0);
        floatx16 g  = __builtin_amdgcn_mfma_f32_32x32x16_bf16(afL, bl, zc, 0, 0, 0);
        g = __builtin_amdgcn_mfma_f32_32x32x16_bf16(afH, bh, g, 0, 0, 0);
#pragma unroll
        for (int r = 0; r < 16; ++r) {
            float t = __builtin_amdgcn_exp2f(ar[r]) * g[r];
            if ((r & 3) == 0) m0 += t;
            else if ((r & 3) == 1) m1 += t;
            else if ((r & 3) == 2) m2 += t;
            else m3 += t;
        }
    };
    auto jobD = [&](short8 ba, short8 bl, short8 bh) {
        floatx16 ar = __builtin_amdgcn_mfma_f32_32x32x16_bf16(afA, ba, zc, 0, 0, 0);
        floatx16 g  = __builtin_amdgcn_mfma_f32_32x32x16_bf16(afL, bl, zc, 0, 0, 0);
        g = __builtin_amdgcn_mfma_f32_32x32x16_bf16(afH, bh, g, 0, 0, 0);
#pragma unroll
        for (int r = 0; r < 16; ++r) {
            float t = __builtin_amdgcn_exp2f(ar[r]) * g[r];
            if ((r & 3) == 0) d0 += t;
            else if ((r & 3) == 1) d1 += t;
            else if ((r & 3) == 2) d2 += t;
            else d3 += t;
        }
    };

    auto load_A = [&](int ti) {
        int rr = ti * 32 + l32;
        afA = *(const short8*)(argA + rr * 32 + l5 * 16);
        afL = *(const short8*)(segT + rr * 48 + l5 * 16);
        afH = l5 ? *(const short8*)zp : *(const short8*)(segT + rr * 48 + 32);
    };

    // Main phase: j-tiles jbase+c, +CHUNKS, ... while index < jbase+cnt.
    // 4-slot static pipeline: slot k holds job t+k; reload slot k for job
    // t+4+k immediately after its MFMAs consume it.
    auto run_main = [&](int jbase, int cnt) {
        if (cnt <= c) return;
        int nj = (cnt - c + CHUNKS - 1) / CHUNKS;
        int j0 = jbase + c;
        const int dA = CHUNKS * 1024, dS = CHUNKS * 1536;
        int oA = j0 * 1024, oS = j0 * 1536;

        short8 a0, l0, h0, a1, l1, h1, a2, l2, h2, a3, l3, h3;
        a0 = *(const short8*)(bBa + oA);
        l0 = *(const short8*)(bBs + oS);
        h0 = *(const short8*)(bBh + (oS & maskH));
        a1 = a0; l1 = l0; h1 = h0;
        a2 = a0; l2 = l0; h2 = h0;
        a3 = a0; l3 = l0; h3 = h0;
        if (nj > 1) {
            a1 = *(const short8*)(bBa + oA + dA);
            l1 = *(const short8*)(bBs + oS + dS);
            h1 = *(const short8*)(bBh + ((oS + dS) & maskH));
        }
        if (nj > 2) {
            a2 = *(const short8*)(bBa + oA + 2 * dA);
            l2 = *(const short8*)(bBs + oS + 2 * dS);
            h2 = *(const short8*)(bBh + ((oS + 2 * dS) & maskH));
        }
        if (nj > 3) {
            a3 = *(const short8*)(bBa + oA + 3 * dA);
            l3 = *(const short8*)(bBs + oS + 3 * dS);
            h3 = *(const short8*)(bBh + ((oS + 3 * dS) & maskH));
        }
        for (int t = 0; t < nj; t += 4) {
            jobM(a0, l0, h0);
            if (t + 4 < nj) {
                a0 = *(const short8*)(bBa + oA + 4 * dA);
                l0 = *(const short8*)(bBs + oS + 4 * dS);
                h0 = *(const short8*)(bBh + ((oS + 4 * dS) & maskH));
            }
            if (t + 1 < nj) {
                jobM(a1, l1, h1);
                if (t + 5 < nj) {
                    a1 = *(const short8*)(bBa + oA + 5 * dA);
                    l1 = *(const short8*)(bBs + oS + 5 * dS);
                    h1 = *(const short8*)(bBh + ((oS + 5 * dS) & maskH));
                }
            }
            if (t + 2 < nj) {
                jobM(a2, l2, h2);
                if (t + 6 < nj) {
                    a2 = *(const short8*)(bBa + oA + 6 * dA);
                    l2 = *(const short8*)(bBs + oS + 6 * dS);
                    h2 = *(const short8*)(bBh + ((oS + 6 * dS) & maskH));
                }
            }
            if (t + 3 < nj) {
                jobM(a3, l3, h3);
                if (t + 7 < nj) {
                    a3 = *(const short8*)(bBa + oA + 7 * dA);
                    l3 = *(const short8*)(bBs + oS + 7 * dS);
                    h3 = *(const short8*)(bBh + ((oS + 7 * dS) & maskH));
                }
            }
            oA += 4 * dA; oS += 4 * dS;
        }
    };

    // Strip-diagonal 4x4 tile block: wave ii handles j-tiles [4s+ii, 4s+4).
    auto run_edge = [&](int s) {
        for (int jj = wave; jj < 4; ++jj) {
            int j = 4 * s + jj;
            int oA = j * 1024, oS = j * 1536;
            short8 ba = *(const short8*)(bBa + oA);
            short8 bl = *(const short8*)(bBs + oS);
            short8 bh = *(const short8*)(bBh + (oS & maskH));
            if (jj == wave) jobD(ba, bl, bh);   // diag tile, weight 1 (symmetric)
            else           jobM(ba, bl, bh);    // off-diag, weight 2
        }
    };

    const int s0 = sp, s1 = 31 - sp;

    load_A(4 * s0 + wave);
    run_main(4 * s0 + 4, 124 - 4 * sp);
    if (c == CHUNKS - 1) run_edge(s0);

    load_A(4 * s1 + wave);
    run_main(4 * s1 + 4, 4 * sp);
    if (c == CHUNKS - 2) run_edge(s1);

    float part = 2.0f * ((m0 + m1) + (m2 + m3)) + ((d0 + d1) + (d2 + d3));
#pragma unroll
    for (int off = 32; off > 0; off >>= 1)
        part += __shfl_down(part, off, 64);
    __shared__ float wsum[4];
    if (lane == 0) wsum[wave] = part;
    __syncthreads();
    if (threadIdx.x == 0) {
        int blin = (n * 16 + sp) * CHUNKS + c;   // [0, NBLOCKS)
        ((float*)(wsb + PART_OFF))[blin] =
            (wsum[0] + wsum[1]) + (wsum[2] + wsum[3]);
    }
}

__global__ void crf_reduce(const char* __restrict__ wsb,
                           float* __restrict__ out)
{
    const float* part = (const float*)(wsb + PART_OFF);
    int t = threadIdx.x;                 // 256 threads, 2048 partials
    float s = 0.0f;
#pragma unroll
    for (int i = 0; i < NBLOCKS / 256; ++i)
        s += part[t + i * 256];
#pragma unroll
    for (int off = 32; off > 0; off >>= 1)
        s += __shfl_down(s, off, 64);
    __shared__ float wsum[4];
    if ((t & 63) == 0) wsum[t >> 6] = s;
    __syncthreads();
    if (t == 0)
        out[0] = ((wsum[0] + wsum[1]) + (wsum[2] + wsum[3])) * OUT_SCALE;
}

extern "C" void kernel_launch(void* const* d_in, const int* in_sizes, int n_in,
                              void* d_out, int out_size, void* d_ws, size_t ws_size,
                              hipStream_t stream)
{
    const float* images = (const float*)d_in[0];   // [4,3,128,128]
    const float* segm   = (const float*)d_in[1];   // [4,21,128,128]
    float* out = (float*)d_out;                    // [1]
    char* wsb = (char*)d_ws;                       // ~1.85 MB used

    int prep_threads = NFEAT + NSEG2;
    crf_prep<<<dim3((prep_threads + 255) / 256), dim3(256), 0, stream>>>(
        images, segm, wsb);
    crf_pair<<<dim3(CHUNKS, 16, N_BATCH), dim3(256), 0, stream>>>(wsb);
    crf_reduce<<<dim3(1), dim3(256), 0, stream>>>(wsb, out);
}

// Round 9
// 70.649 us; speedup vs baseline: 1.0413x; 1.0406x over previous
//
#include <hip/hip_runtime.h>

// ColorDenseCRFLoss via 32x32x16 MFMA + triangle symmetry.
// out = -1e-7/4 * sum_{n,p,q} exp(-0.5*||f_p-f_q||^2) * (seg_p . seg_q)
// R9 = revert to R3 (best measured: 71.0us). Evidence across R0-R8: MFMA
// count /2.7 (R0), TLP x2 (R6), ILP depth x2 (R8) all null within noise;
// fused tails lose (R4 +41.7, R7 +2.0); only real win was removing the
// same-address atomic storm (R3, -7.7). Decomposition: ~41us harness poison
// fill + ~20us restore dispatches/gaps + <=10us our 3 kernels. At the
// harness floor; structure below is the best-measured configuration.

#define N_BATCH 4
#define IH 128
#define IW 128
#define P 4096   // 64x64 downsampled pixels per batch
#define KC 21

using short8   = __attribute__((ext_vector_type(8))) short;
using floatx16 = __attribute__((ext_vector_type(16))) float;

static constexpr float INV_SIGMA = 1.0f / 15.0f;
static constexpr float LOG2E     = 1.4426950408889634f;
static constexpr float OUT_SCALE = -1e-7f / 4.0f;

// ws layout (bytes):
//   [0,64)  zero page; argA/argB: rows x 32B; seg: rows x 48B; partials
#define ZP_OFF   0
#define ARGA_OFF 64
#define ARGB_OFF (ARGA_OFF + N_BATCH * P * 32)
#define SEG_OFF  (ARGB_OFF + N_BATCH * P * 32)
#define PART_OFF (SEG_OFF + N_BATCH * P * 48)   // 1024 floats

#define NFEAT (N_BATCH * P)              // 16384
#define NSEG2 (N_BATCH * KC * P / 2)     // 172032 (2 pixels/thread)

#define CHUNKS 16
#define NBLOCKS (CHUNKS * 16 * N_BATCH)  // 1024 crf_pair blocks

__device__ __forceinline__ ushort f2bf(float x) {  // RNE float->bf16 bits
    unsigned u = __builtin_bit_cast(unsigned, x);
    unsigned r = (u + 0x7FFFu + ((u >> 16) & 1u)) >> 16;
    return (ushort)r;
}
__device__ __forceinline__ float bf2f(ushort h) {
    return __builtin_bit_cast(float, (unsigned)h << 16);
}

__global__ void crf_prep(const float* __restrict__ img,
                         const float* __restrict__ seg,
                         char* __restrict__ wsb)
{
    int t = blockIdx.x * blockDim.x + threadIdx.x;
    if (t < NFEAT) {
        if (t < 16) ((float*)(wsb + ZP_OFF))[t] = 0.0f;  // zero page

        int n = t >> 12;
        int p = t & (P - 1);
        int y = p >> 6, x = p & 63;

        const float* ib = img + (size_t)n * 3 * IH * IW + (size_t)(2 * y) * IW + 2 * x;
        float f0 = ib[0] * INV_SIGMA;
        float f1 = ib[IH * IW] * INV_SIGMA;
        float f2 = ib[2 * IH * IW] * INV_SIGMA;
        float h = 0.5f * (f0 * f0 + f1 * f1 + f2 * f2);

        float fa0 = f0 * LOG2E, fa1 = f1 * LOG2E, fa2 = f2 * LOG2E;
        ushort ah0 = f2bf(fa0), ah1 = f2bf(fa1), ah2 = f2bf(fa2);
        ushort al0 = f2bf(fa0 - bf2f(ah0));
        ushort al1 = f2bf(fa1 - bf2f(ah1));
        ushort al2 = f2bf(fa2 - bf2f(ah2));
        float nhL = -h * LOG2E;
        ushort nhh = f2bf(nhL), nhl = f2bf(nhL - bf2f(nhh));
        ushort bh0 = f2bf(f0), bh1 = f2bf(f1), bh2 = f2bf(f2);
        ushort bl0 = f2bf(f0 - bf2f(bh0));
        ushort bl1 = f2bf(f1 - bf2f(bh1));
        ushort bl2 = f2bf(f2 - bf2f(bh2));
        float hL = h * LOG2E;
        ushort hbh = f2bf(hL), hbl = f2bf(hL - bf2f(hbh));

        const ushort ONE = 0x3F80, NEG1 = 0xBF80;
        // dot(argA_p, argB_q) = log2e * (f_p.f_q - h_p - h_q), exactly K=16
        ushort rA[16] = {ah0, ah1, ah2, ah0, ah1, ah2, al0, al1, al2, al0, al1, al2,
                         nhh, nhl, NEG1, NEG1};
        ushort rB[16] = {bh0, bh1, bh2, bl0, bl1, bl2, bh0, bh1, bh2, bl0, bl1, bl2,
                         ONE, ONE, hbh, hbl};

        short8 vA0, vA1, vB0, vB1;
#pragma unroll
        for (int j = 0; j < 8; ++j) {
            vA0[j] = (short)rA[j];     vA1[j] = (short)rA[8 + j];
            vB0[j] = (short)rB[j];     vB1[j] = (short)rB[8 + j];
        }
        short8* dA = (short8*)(wsb + ARGA_OFF + (size_t)t * 32);
        dA[0] = vA0; dA[1] = vA1;
        short8* dB = (short8*)(wsb + ARGB_OFF + (size_t)t * 32);
        dB[0] = vB0; dB[1] = vB1;

        char* sp = wsb + SEG_OFF + (size_t)t * 48;   // zero seg pad k=21..23
        *(ushort*)(sp + 42) = 0;
        *(uint*)(sp + 44) = 0;
    } else if (t < NFEAT + NSEG2) {
        int u = t - NFEAT;
        int pp = (u & 2047) * 2;     // pixel pair base (even)
        int nk = u >> 11;            // n*21 + k
        int n = nk / 21;
        int k = nk - n * 21;
        int y = pp >> 6, x0 = pp & 63;

        const float* r0 = seg + (size_t)nk * IH * IW + (size_t)(2 * y) * IW + 2 * x0;
        float4 a = *(const float4*)r0;
        float4 b = *(const float4*)(r0 + IW);
        float v0 = 0.25f * ((a.x + a.y) + (b.x + b.y));
        float v1 = 0.25f * ((a.z + a.w) + (b.z + b.w));
        char* d = wsb + SEG_OFF + (size_t)(n * P + pp) * 48 + k * 2;
        *(ushort*)d = f2bf(v0);
        *(ushort*)(d + 48) = f2bf(v1);
    }
}

__global__ __launch_bounds__(256, 4) void crf_pair(char* __restrict__ wsb)
{
    const int n    = blockIdx.z;
    const int sp   = blockIdx.y;          // strip pair [0,16): strips sp, 31-sp
    const int c    = blockIdx.x;          // j-chunk [0,CHUNKS)
    const int wave = threadIdx.x >> 6;    // i-tile within strip [0,4)
    const int lane = threadIdx.x & 63;
    const int l32  = lane & 31;
    const int l5   = lane >> 5;           // k-half select

    const char* argA = wsb + ARGA_OFF + (size_t)n * P * 32;
    const char* argB = wsb + ARGB_OFF + (size_t)n * P * 32;
    const char* segT = wsb + SEG_OFF  + (size_t)n * P * 48;
    const char* zp   = wsb + ZP_OFF;

    // B-side per-lane bases; j-tile strides 1024B (arg) / 1536B (seg)
    const char* bBa = argB + l32 * 32 + l5 * 16;
    const char* bBs = segT + l32 * 48 + l5 * 16;
    const int maskH = l5 ? 0 : ~0;        // hi seg half: k>=24 is zero pad
    const char* bBh = l5 ? zp : (segT + l32 * 48 + 32);

    const floatx16 zc = {0.f,0.f,0.f,0.f,0.f,0.f,0.f,0.f,
                         0.f,0.f,0.f,0.f,0.f,0.f,0.f,0.f};

    short8 afA, afL, afH;                 // A fragments for current phase

    float m0=0.f, m1=0.f, m2=0.f, m3=0.f; // weight-2 partials
    float d0=0.f, d1=0.f, d2=0.f, d3=0.f; // weight-1 (diag tile) partials

    auto jobM = [&](short8 ba, short8 bl, short8 bh) {
        floatx16 ar = __builtin_amdgcn_mfma_f32_32x32x16_bf16(afA, ba, zc, 0, 0, 0);
        floatx16 g  = __builtin_amdgcn_mfma_f32_32x32x16_bf16(afL, bl, zc, 0, 0, 0);
        g = __builtin_amdgcn_mfma_f32_32x32x16_bf16(afH, bh, g, 0, 0, 0);
#pragma unroll
        for (int r = 0; r < 16; ++r) {
            float t = __builtin_amdgcn_exp2f(ar[r]) * g[r];
            if ((r & 3) == 0) m0 += t;
            else if ((r & 3) == 1) m1 += t;
            else if ((r & 3) == 2) m2 += t;
            else m3 += t;
        }
    };
    auto jobD = [&](short8 ba, short8 bl, short8 bh) {
        floatx16 ar = __builtin_amdgcn_mfma_f32_32x32x16_bf16(afA, ba, zc, 0, 0, 0);
        floatx16 g  = __builtin_amdgcn_mfma_f32_32x32x16_bf16(afL, bl, zc, 0, 0, 0);
        g = __builtin_amdgcn_mfma_f32_32x32x16_bf16(afH, bh, g, 0, 0, 0);
#pragma unroll
        for (int r = 0; r < 16; ++r) {
            float t = __builtin_amdgcn_exp2f(ar[r]) * g[r];
            if ((r & 3) == 0) d0 += t;
            else if ((r & 3) == 1) d1 += t;
            else if ((r & 3) == 2) d2 += t;
            else d3 += t;
        }
    };

    auto load_A = [&](int ti) {
        int rr = ti * 32 + l32;
        afA = *(const short8*)(argA + rr * 32 + l5 * 16);
        afL = *(const short8*)(segT + rr * 48 + l5 * 16);
        afH = l5 ? *(const short8*)zp : *(const short8*)(segT + rr * 48 + 32);
    };

    // Main phase: j-tiles jbase+c, +CHUNKS, ... while index < jbase+cnt.
    // 2-slot ping-pong; reload a slot right after its MFMAs consumed it.
    auto run_main = [&](int jbase, int cnt) {
        if (cnt <= c) return;
        int nj = (cnt - c + CHUNKS - 1) / CHUNKS;
        int j0 = jbase + c;
        int oA0 = j0 * 1024, oS0 = j0 * 1536;
        int oA1 = oA0 + CHUNKS * 1024, oS1 = oS0 + CHUNKS * 1536;
        short8 a0 = *(const short8*)(bBa + oA0);
        short8 l0 = *(const short8*)(bBs + oS0);
        short8 h0 = *(const short8*)(bBh + (oS0 & maskH));
        short8 a1 = a0, l1 = l0, h1 = h0;
        if (nj > 1) {
            a1 = *(const short8*)(bBa + oA1);
            l1 = *(const short8*)(bBs + oS1);
            h1 = *(const short8*)(bBh + (oS1 & maskH));
        }
        for (int t = 0; t < nj; t += 2) {
            jobM(a0, l0, h0);
            if (t + 2 < nj) {
                oA0 += 2 * CHUNKS * 1024; oS0 += 2 * CHUNKS * 1536;
                a0 = *(const short8*)(bBa + oA0);
                l0 = *(const short8*)(bBs + oS0);
                h0 = *(const short8*)(bBh + (oS0 & maskH));
            }
            if (t + 1 < nj) {
                jobM(a1, l1, h1);
                if (t + 3 < nj) {
                    oA1 += 2 * CHUNKS * 1024; oS1 += 2 * CHUNKS * 1536;
                    a1 = *(const short8*)(bBa + oA1);
                    l1 = *(const short8*)(bBs + oS1);
                    h1 = *(const short8*)(bBh + (oS1 & maskH));
                }
            }
        }
    };

    // Strip-diagonal 4x4 tile block: wave ii handles j-tiles [4s+ii, 4s+4).
    auto run_edge = [&](int s) {
        for (int jj = wave; jj < 4; ++jj) {
            int j = 4 * s + jj;
            int oA = j * 1024, oS = j * 1536;
            short8 ba = *(const short8*)(bBa + oA);
            short8 bl = *(const short8*)(bBs + oS);
            short8 bh = *(const short8*)(bBh + (oS & maskH));
            if (jj == wave) jobD(ba, bl, bh);   // diag tile, weight 1 (symmetric)
            else           jobM(ba, bl, bh);    // off-diag, weight 2
        }
    };

    const int s0 = sp, s1 = 31 - sp;

    load_A(4 * s0 + wave);
    run_main(4 * s0 + 4, 124 - 4 * sp);
    if (c == CHUNKS - 1) run_edge(s0);

    load_A(4 * s1 + wave);
    run_main(4 * s1 + 4, 4 * sp);
    if (c == CHUNKS - 2) run_edge(s1);

    float part = 2.0f * ((m0 + m1) + (m2 + m3)) + ((d0 + d1) + (d2 + d3));
#pragma unroll
    for (int off = 32; off > 0; off >>= 1)
        part += __shfl_down(part, off, 64);
    __shared__ float wsum[4];
    if (lane == 0) wsum[wave] = part;
    __syncthreads();
    if (threadIdx.x == 0) {
        int blin = (n * 16 + sp) * CHUNKS + c;   // [0, NBLOCKS)
        ((float*)(wsb + PART_OFF))[blin] =
            (wsum[0] + wsum[1]) + (wsum[2] + wsum[3]);
    }
}

__global__ void crf_reduce(const char* __restrict__ wsb,
                           float* __restrict__ out)
{
    const float* part = (const float*)(wsb + PART_OFF);
    int t = threadIdx.x;                 // 256 threads, 1024 partials
    float s = (part[t] + part[t + 256]) + (part[t + 512] + part[t + 768]);
#pragma unroll
    for (int off = 32; off > 0; off >>= 1)
        s += __shfl_down(s, off, 64);
    __shared__ float wsum[4];
    if ((t & 63) == 0) wsum[t >> 6] = s;
    __syncthreads();
    if (t == 0)
        out[0] = ((wsum[0] + wsum[1]) + (wsum[2] + wsum[3])) * OUT_SCALE;
}

extern "C" void kernel_launch(void* const* d_in, const int* in_sizes, int n_in,
                              void* d_out, int out_size, void* d_ws, size_t ws_size,
                              hipStream_t stream)
{
    const float* images = (const float*)d_in[0];   // [4,3,128,128]
    const float* segm   = (const float*)d_in[1];   // [4,21,128,128]
    float* out = (float*)d_out;                    // [1]
    char* wsb = (char*)d_ws;                       // ~1.84 MB used

    int prep_threads = NFEAT + NSEG2;
    crf_prep<<<dim3((prep_threads + 255) / 256), dim3(256), 0, stream>>>(
        images, segm, wsb);
    crf_pair<<<dim3(CHUNKS, 16, N_BATCH), dim3(256), 0, stream>>>(wsb);
    crf_reduce<<<dim3(1), dim3(256), 0, stream>>>(wsb, out);
}